// Round 5
// baseline (206.059 us; speedup 1.0000x reference)
//
#include <hip/hip_runtime.h>

// out[b, w, j] = sum_p x[b,j,p] * weight[j,p,w] + bias[j,w]
// x: [B, M, P] f32, weight: [M, P, W] f32, bias: [M, W] f32, out: [B, W, M] f32
// B=128, M=10000, P=64, W=24. HBM floor ~513 MB -> ~81 us.
//
// Round-5: round-4 was LDS-read-throughput-bound (384 b128 broadcast reads /
// thread @ ~12cyc = ~150us aggregate). Fix: thread = 4 b-rows x 12 w
// (acc[4][12]) -> 16 FMA per weight b128 read -> LDS time ~37us < HBM floor.
// Wave = 32 b-lanes x 2 w-halves (paired lanes issue identical x addresses ->
// TA dedup). BH=128 (all b in block) -> weight fetched exactly once.
// obuf[w][j][bl]: transpose writes lane==bank (conflict-free). Bijective XCD
// swizzle so adjacent j-tiles share an L2 (32B store-run combining).

constexpr int B = 128;
constexpr int M = 10000;
constexpr int P = 64;
constexpr int W = 24;

constexpr int JT = 8;     // j per block (= waves per block)
constexpr int NT = 512;   // 8 waves
constexpr int NWG = M / JT;  // 1250

__global__ __launch_bounds__(NT, 4) void pcl_kernel(
    const float* __restrict__ x, const float* __restrict__ wgt,
    const float* __restrict__ bias, float* __restrict__ out) {
  __shared__ float wlds[JT * P * W];  // [j][p][w] fp32: 48 KiB (== global layout)
  __shared__ float obuf[W][JT][32];   // [w][j][bl]: 24 KiB (total 73,728 B)

  const int t = threadIdx.x;

  // bijective XCD-aware swizzle (m204): 1250 = 8*156 + 2
  const int orig = blockIdx.x;
  const int xcd = orig & 7;
  const int idx = orig >> 3;
  const int jt = (xcd < 2 ? xcd * 157 : 314 + (xcd - 2) * 156) + idx;
  const int j0 = jt * JT;

  // ---- stage weight tile: straight coalesced float4 copy ----
  {
    const float4* wg4 =
        reinterpret_cast<const float4*>(wgt + (size_t)j0 * (P * W));
    float4* wl4 = reinterpret_cast<float4*>(wlds);
#pragma unroll
    for (int k = 0; k < (JT * P * W / 4) / NT; ++k)  // 6 float4/thread
      wl4[t + k * NT] = wg4[t + k * NT];
  }

  const int jw = t >> 6;      // wave index = local j
  const int lane = t & 63;
  const int bl = lane & 31;   // b-lane
  const int wh = lane >> 5;   // w-half
  const int w0 = 12 * wh;
  const int j = j0 + jw;

  // bias -> 4x12 accumulators
  float acc[4][12];
  {
    const float4* bp =
        reinterpret_cast<const float4*>(bias + (size_t)j * W + w0);
    float4 b0v = bp[0], b1v = bp[1], b2v = bp[2];
    const float bb[12] = {b0v.x, b0v.y, b0v.z, b0v.w, b1v.x, b1v.y,
                          b1v.z, b1v.w, b2v.x, b2v.y, b2v.z, b2v.w};
#pragma unroll
    for (int bi = 0; bi < 4; ++bi)
#pragma unroll
      for (int ww = 0; ww < 12; ++ww) acc[bi][ww] = bb[ww];
  }

  const float* wj = wlds + jw * (P * W) + w0;
  const float4* xp0 = reinterpret_cast<const float4*>(x + ((size_t)(bl + 0) * M + j) * P);
  const float4* xp1 = reinterpret_cast<const float4*>(x + ((size_t)(bl + 32) * M + j) * P);
  const float4* xp2 = reinterpret_cast<const float4*>(x + ((size_t)(bl + 64) * M + j) * P);
  const float4* xp3 = reinterpret_cast<const float4*>(x + ((size_t)(bl + 96) * M + j) * P);

  __syncthreads();  // weights staged

  // ---- compute: per chunk c (4 p's): 4 x-loads, 12 LDS b128, 192 FMA ----
#pragma unroll 2
  for (int c = 0; c < P / 4; ++c) {
    float4 xv[4] = {xp0[c], xp1[c], xp2[c], xp3[c]};
#pragma unroll
    for (int pp = 0; pp < 4; ++pp) {
      const float4* wp =
          reinterpret_cast<const float4*>(wj + (size_t)(4 * c + pp) * W);
      float4 wa = wp[0], wb = wp[1], wc = wp[2];
      const float wv[12] = {wa.x, wa.y, wa.z, wa.w, wb.x, wb.y,
                            wb.z, wb.w, wc.x, wc.y, wc.z, wc.w};
#pragma unroll
      for (int bi = 0; bi < 4; ++bi) {
        const float xs = reinterpret_cast<const float*>(&xv[bi])[pp];
#pragma unroll
        for (int ww = 0; ww < 12; ++ww)
          acc[bi][ww] = fmaf(xs, wv[ww], acc[bi][ww]);
      }
    }
  }

  // ---- store: 4 b-rounds; transpose writes lane==bank; 32B-run float4 ----
#pragma unroll
  for (int r = 0; r < 4; ++r) {
    __syncthreads();  // previous round's drain reads done
#pragma unroll
    for (int ww = 0; ww < 12; ++ww) obuf[w0 + ww][jw][bl] = acc[r][ww];
    __syncthreads();  // obuf visible
#pragma unroll
    for (int it = 0; it < 3; ++it) {
      const int d = t + it * NT;   // 0..1535
      const int blr = d & 31;
      const int e = d >> 5;        // 0..47
      const int jq = e & 1;
      const int w = e >> 1;        // 0..23
      float4 o;
      o.x = obuf[w][4 * jq + 0][blr];
      o.y = obuf[w][4 * jq + 1][blr];
      o.z = obuf[w][4 * jq + 2][blr];
      o.w = obuf[w][4 * jq + 3][blr];
      *reinterpret_cast<float4*>(
          out + ((size_t)(32 * r + blr) * W + w) * M + j0 + 4 * jq) = o;
    }
  }
}

extern "C" void kernel_launch(void* const* d_in, const int* in_sizes, int n_in,
                              void* d_out, int out_size, void* d_ws, size_t ws_size,
                              hipStream_t stream) {
  const float* x    = (const float*)d_in[0];
  const float* wgt  = (const float*)d_in[1];
  const float* bias = (const float*)d_in[2];
  float* out        = (float*)d_out;

  dim3 grid(NWG);  // 1250
  dim3 block(NT);  // 512
  hipLaunchKernelGGL(pcl_kernel, grid, block, 0, stream, x, wgt, bias, out);
}